// Round 23
// baseline (540.922 us; speedup 1.0000x reference)
//
#include <hip/hip_runtime.h>
#include <math.h>

// DigitCaps dynamic routing — R22b: btile-local fusion (compile fix of R22).
// 512 blocks; group g (=btile) = 16 blocks on ONE XCD (bid = xcd+8*(slot+4*k)).
// Each block: iter0 -> group-barrier -> local squash (V in LDS) -> iter1 ->
// barrier -> squash -> iter2 -> barrier -> squash -> (k==0) write out.
// Inner math byte-identical to R15b champion. S_part double-buffered.
#define J 10
#define BT 16
#define NBT 32
#define NIC 16
#define ICB 72
#define IPW 18
#define JD 160
#define BATCH 512
#define IN_CAPS 1152
#define RTH 256
#define VP 164        // V_lds row stride (pad: 164%32=4 -> banks vary with b)

typedef __attribute__((ext_vector_type(8))) short short8;
typedef __attribute__((ext_vector_type(4))) float f32x4;
typedef __attribute__((ext_vector_type(4))) __fp16 fp16x4;
typedef __attribute__((ext_vector_type(2))) __fp16 fp16x2;

__device__ inline short f2bf(float f) {
    union { float f; unsigned u; } v; v.f = f;
    return (short)((v.u + 0x7FFFu + ((v.u >> 16) & 1u)) >> 16);  // RNE
}
__device__ inline short8 cvt8(float4 a, float4 b) {
    short8 o;
    o[0] = f2bf(a.x); o[1] = f2bf(a.y); o[2] = f2bf(a.z); o[3] = f2bf(a.w);
    o[4] = f2bf(b.x); o[5] = f2bf(b.y); o[6] = f2bf(b.z); o[7] = f2bf(b.w);
    return o;
}

__global__ __launch_bounds__(256) void convert_w(
    const float* __restrict__ W, short* __restrict__ Wb)
{
    const int t = blockIdx.x * 256 + threadIdx.x;   // 184320 threads exactly
    const float4* src = (const float4*)W + (size_t)t * 2;
    *(short8*)(Wb + (size_t)t * 8) = cvt8(src[0], src[1]);
}

#define TI 32
#define TB 64
__global__ __launch_bounds__(256) void transpose_x(
    const float* __restrict__ X, short* __restrict__ Xb)
{
    __shared__ short8 tile[TI][TB + 1];
    const int it = blockIdx.x % (IN_CAPS / TI);
    const int bt = blockIdx.x / (IN_CAPS / TI);
    const int t  = threadIdx.x;

    const int i_l = t & 31, b_s = t >> 5;
#pragma unroll
    for (int p = 0; p < 8; ++p) {
        const int b_l = p * 8 + b_s;
        const float4* src = (const float4*)(X +
            (((size_t)(bt * TB + b_l)) * IN_CAPS + it * TI + i_l) * 8);
        tile[i_l][b_l] = cvt8(src[0], src[1]);
    }
    __syncthreads();
    const int b_l = t & 63, i_s = t >> 6;
#pragma unroll
    for (int p = 0; p < 8; ++p) {
        const int i_l2 = p * 4 + i_s;
        *(short8*)(Xb + (((size_t)(it * TI + i_l2)) * BATCH + bt * TB + b_l) * 8)
            = tile[i_l2][b_l];
    }
}

// group barrier: monotonic counter, thread0 arrives+spins, agent scope.
__device__ inline void group_barrier(int* cnt, int g, int target)
{
    __syncthreads();
    if (threadIdx.x == 0) {
        __threadfence();
        __hip_atomic_fetch_add(&cnt[g], 1, __ATOMIC_RELEASE,
                               __HIP_MEMORY_SCOPE_AGENT);
        while (__hip_atomic_load(&cnt[g], __ATOMIC_ACQUIRE,
                                 __HIP_MEMORY_SCOPE_AGENT) < target) {}
        __threadfence();
    }
    __syncthreads();
}

extern "C" __global__ void __launch_bounds__(RTH, 2) fused_route(
    const short* __restrict__ Xb, const short* __restrict__ Wb,
    float* __restrict__ S0, float* __restrict__ S1,
    int* __restrict__ cnt, float* __restrict__ out)
{
    __shared__ float s_lds[BT][JD + 1];     // per-iter reduce slab (10.3 KB)
    __shared__ float V_lds[BT * VP];        // running V for this btile (10.5 KB)

    const int tid  = threadIdx.x, bid = blockIdx.x;
    const int lane = tid & 63, wave = tid >> 6;
    // group decode: bid = xcd + 8*(slot + 4*k); members share the XCD.
    const int xcd = bid & 7, slot = (bid >> 3) & 3, k = bid >> 5;
    const int g = xcd * 4 + slot;          // btile 0..31
    const int icb = k;                      // member = i-chunk 0..15
    const int bcol = lane & 15, kg = lane >> 4;
    const int b = g * BT + bcol;

    fp16x4 ones;
    ones[0] = (__fp16)1.0f; ones[1] = (__fp16)1.0f;
    ones[2] = (__fp16)1.0f; ones[3] = (__fp16)1.0f;
    const short8 zero8 = (short8)(short)0;

    // ================= iter 0: c = 0.1, K=32-packed GEMM =================
    for (int t = tid; t < BT * (JD + 1); t += RTH) (&s_lds[0][0])[t] = 0.f;
    __syncthreads();
    {
        f32x4 acc[J];
#pragma unroll
        for (int j = 0; j < J; ++j) acc[j] = (f32x4)(0.f);
        for (int ks = wave; ks < ICB / 4; ks += 4) {
            const int ia = icb * ICB + ks * 4 + kg;
            const short8 bfr = *(const short8*)(Xb + ((size_t)ia * BATCH + b) * 8);
            short8 afr[J];
#pragma unroll
            for (int j = 0; j < J; ++j)
                afr[j] = *(const short8*)(Wb + (size_t)ia * 1280 + j * 128 + bcol * 8);
#pragma unroll
            for (int j = 0; j < J; ++j)
                acc[j] = __builtin_amdgcn_mfma_f32_16x16x32_bf16(afr[j], bfr, acc[j], 0, 0, 0);
        }
#pragma unroll
        for (int j = 0; j < J; ++j)
#pragma unroll
            for (int r = 0; r < 4; ++r)
                atomicAdd(&s_lds[bcol][j * 16 + kg * 4 + r], 0.1f * acc[j][r]);
    }
    __syncthreads();
    for (int t = tid; t < BT * JD; t += RTH)
        S0[((size_t)icb * BATCH + g * BT + t / JD) * JD + (t % JD)]
            = (&s_lds[0][0])[(t / JD) * (JD + 1) + (t % JD)];

    group_barrier(cnt, g, 16);

    // ======== local squash: V_lds = squash(sum over 16 slabs of S0) ========
#pragma unroll
    for (int it = 0; it < 10; ++it) {
        const int e = tid + it * 256;           // 2560 = 16 b x 160 jd
        const int bb = e / JD, p = e % JD;
        float s = 0.f;
#pragma unroll
        for (int ic = 0; ic < NIC; ++ic)
            s += S0[((size_t)ic * BATCH + g * BT + bb) * JD + p];
        float sq = s * s;
        sq += __shfl_xor(sq, 1);
        sq += __shfl_xor(sq, 2);
        sq += __shfl_xor(sq, 4);
        sq += __shfl_xor(sq, 8);
        V_lds[bb * VP + p] = s * sq / ((1.f + sq) * sqrtf(sq + 1e-8f));
    }
    __syncthreads();

    // ================= iters 1 & 2: routed (R15b inner loop) =================
#pragma unroll 1
    for (int iter = 1; iter <= 2; ++iter) {
        float* Sw = (iter == 1) ? S1 : S0;      // double-buffer (race-free)

        for (int t = tid; t < BT * (JD + 1); t += RTH) (&s_lds[0][0])[t] = 0.f;
        __syncthreads();

        float4 Vr[J];
#pragma unroll
        for (int j = 0; j < J; ++j)
            Vr[j] = *(const float4*)&V_lds[bcol * VP + j * 16 + kg * 4];

        float s_acc[J][4];
#pragma unroll
        for (int j = 0; j < J; ++j)
#pragma unroll
            for (int r = 0; r < 4; ++r) s_acc[j][r] = 0.f;

        const int i0w = icb * ICB + wave * IPW;

#pragma unroll
        for (int gi = 0; gi < 5; ++gi) {
            const int nt = (gi < 4) ? 4 : 2;
            int ia = i0w + gi * 4 + kg;
            if (ia > IN_CAPS - 1) ia = IN_CAPS - 1;   // tail clamp (masked)

            short8 afr[J];
#pragma unroll
            for (int j = 0; j < J; ++j)
                afr[j] = *(const short8*)(Wb + (size_t)ia * 1280 + j * 128 + bcol * 8);
            const short8 bfull = *(const short8*)(Xb + ((size_t)ia * BATCH + b) * 8);

            for (int t = 0; t < nt; ++t) {
                const short8 bt = (kg == t) ? bfull : zero8;
                f32x4 u[J];
#pragma unroll
                for (int j = 0; j < J; ++j)
                    u[j] = __builtin_amdgcn_mfma_f32_16x16x32_bf16(afr[j], bt, (f32x4)(0.f), 0, 0, 0);

                float L[J];
#pragma unroll
                for (int j = 0; j < J; ++j) {
                    const float p0 = u[j][0] * Vr[j].x;
                    const float p1 = u[j][1] * Vr[j].y;
                    const float p2 = u[j][2] * Vr[j].z;
                    const float p3 = u[j][3] * Vr[j].w;
                    const fp16x2 a01 = __builtin_amdgcn_cvt_pkrtz(p0, p1);
                    const fp16x2 a23 = __builtin_amdgcn_cvt_pkrtz(p2, p3);
                    fp16x4 pb;
                    pb[0] = a01[0]; pb[1] = a01[1];
                    pb[2] = a23[0]; pb[3] = a23[1];
                    const f32x4 Lr = __builtin_amdgcn_mfma_f32_16x16x16f16(
                        ones, pb, (f32x4)(0.f), 0, 0, 0);
                    L[j] = Lr[0];
                }
                float c[J], Z = 0.f;
#pragma unroll
                for (int j = 0; j < J; ++j) { c[j] = __expf(L[j]); Z += c[j]; }
                const float rz = 1.0f / Z;
#pragma unroll
                for (int j = 0; j < J; ++j) {
                    const float cj = c[j] * rz;
                    s_acc[j][0] += cj * u[j][0];
                    s_acc[j][1] += cj * u[j][1];
                    s_acc[j][2] += cj * u[j][2];
                    s_acc[j][3] += cj * u[j][3];
                }
            }
        }
#pragma unroll
        for (int j = 0; j < J; ++j)
#pragma unroll
            for (int r = 0; r < 4; ++r)
                atomicAdd(&s_lds[bcol][j * 16 + kg * 4 + r], s_acc[j][r]);
        __syncthreads();
        for (int t = tid; t < BT * JD; t += RTH)
            Sw[((size_t)icb * BATCH + g * BT + t / JD) * JD + (t % JD)]
                = (&s_lds[0][0])[(t / JD) * (JD + 1) + (t % JD)];

        group_barrier(cnt, g, 16 * (iter + 1));

        // local squash of Sw
#pragma unroll
        for (int it2 = 0; it2 < 10; ++it2) {
            const int e = tid + it2 * 256;
            const int bb = e / JD, p = e % JD;
            float s = 0.f;
#pragma unroll
            for (int ic = 0; ic < NIC; ++ic)
                s += Sw[((size_t)ic * BATCH + g * BT + bb) * JD + p];
            float sq = s * s;
            sq += __shfl_xor(sq, 1);
            sq += __shfl_xor(sq, 2);
            sq += __shfl_xor(sq, 4);
            sq += __shfl_xor(sq, 8);
            const float v = s * sq / ((1.f + sq) * sqrtf(sq + 1e-8f));
            if (iter == 1) V_lds[bb * VP + p] += v;              // V = v0 + v1
            else if (k == 0) out[(g * BT + bb) * JD + p] = v;    // final: out = v2
        }
        __syncthreads();
    }
}

extern "C" void kernel_launch(void* const* d_in, const int* in_sizes, int n_in,
                              void* d_out, int out_size, void* d_ws, size_t ws_size,
                              hipStream_t stream)
{
    const float* X = (const float*)d_in[0];   // [512][1152][8]
    const float* W = (const float*)d_in[1];   // [1152][10][16][8]
    float* out = (float*)d_out;               // [512][10][16]

    // ws: S0[16][512][160] | S1[16][512][160] (5.24MB each) | Wb bf16 (2.95MB)
    //   | Xb bf16 (9.44MB) | cnt[32]   total ~23.2 MB
    float* S0 = (float*)d_ws;
    float* S1 = S0 + (size_t)NIC * BATCH * JD;
    short* Wb = (short*)(S1 + (size_t)NIC * BATCH * JD);
    short* Xb = Wb + (size_t)IN_CAPS * JD * 8;
    int*   cnt = (int*)(Xb + (size_t)IN_CAPS * BATCH * 8);

    (void)hipMemsetAsync(cnt, 0, 32 * sizeof(int), stream);
    convert_w<<<dim3(720), dim3(256), 0, stream>>>(W, Wb);
    transpose_x<<<dim3((IN_CAPS / TI) * (BATCH / TB)), dim3(256), 0, stream>>>(X, Xb);

    fused_route<<<dim3(512), dim3(RTH), 0, stream>>>(Xb, Wb, S0, S1, cnt, out);
}

// Round 24
// 142.447 us; speedup vs baseline: 3.7974x; 3.7974x over previous
//
#include <hip/hip_runtime.h>
#include <math.h>

// DigitCaps dynamic routing via MFMA u_hat + fused in-register routing.
// R24 = R15b champion, restored verbatim (142.4 us, absmax 0.00195).
// Structure: convert_w | transpose_x | 3x(route, squash).
// route mode-1: 4-i packed loads; per-i u via B-mask (kg==t); logit reduce
// via chained 16x16x16 f16 MFMA (A=ones); per-lane softmax; LDS reduce.
#define J 10
#define BT 16          // batch tile (MFMA N)
#define NBT 32         // BATCH/BT
#define NIC 16         // i-chunks; NIC%8==0 -> same-icb blocks on one XCD
#define ICB 72         // IN_CAPS/NIC
#define IPW 18         // i per wave (4 waves/block)
#define JD 160
#define BATCH 512
#define IN_CAPS 1152
#define RTH 256

typedef __attribute__((ext_vector_type(8))) short short8;
typedef __attribute__((ext_vector_type(4))) float f32x4;
typedef __attribute__((ext_vector_type(4))) __fp16 fp16x4;
typedef __attribute__((ext_vector_type(2))) __fp16 fp16x2;

__device__ inline short f2bf(float f) {
    union { float f; unsigned u; } v; v.f = f;
    return (short)((v.u + 0x7FFFu + ((v.u >> 16) & 1u)) >> 16);  // RNE
}
__device__ inline short8 cvt8(float4 a, float4 b) {
    short8 o;
    o[0] = f2bf(a.x); o[1] = f2bf(a.y); o[2] = f2bf(a.z); o[3] = f2bf(a.w);
    o[4] = f2bf(b.x); o[5] = f2bf(b.y); o[6] = f2bf(b.z); o[7] = f2bf(b.w);
    return o;
}

// W fp32 -> bf16 (same [i][j][d][e] layout), and zero pad-buffer.
__global__ __launch_bounds__(256) void convert_w(
    const float* __restrict__ W, short* __restrict__ Wb, short* __restrict__ zb)
{
    const int t = blockIdx.x * 256 + threadIdx.x;   // 184320 threads exactly
    const float4* src = (const float4*)W + (size_t)t * 2;
    *(short8*)(Wb + (size_t)t * 8) = cvt8(src[0], src[1]);
    if (blockIdx.x == 0 && threadIdx.x < 32) zb[threadIdx.x] = 0;
}

// X fp32 [b][i][e] -> bf16 Xb [i][b][e] (LDS-tiled transpose).
#define TI 32
#define TB 64
__global__ __launch_bounds__(256) void transpose_x(
    const float* __restrict__ X, short* __restrict__ Xb)
{
    __shared__ short8 tile[TI][TB + 1];
    const int it = blockIdx.x % (IN_CAPS / TI);   // 36 i-tiles
    const int bt = blockIdx.x / (IN_CAPS / TI);   // 8 b-tiles
    const int t  = threadIdx.x;

    const int i_l = t & 31, b_s = t >> 5;         // load: 8 b x 32 i per pass
#pragma unroll
    for (int p = 0; p < 8; ++p) {
        const int b_l = p * 8 + b_s;
        const float4* src = (const float4*)(X +
            (((size_t)(bt * TB + b_l)) * IN_CAPS + it * TI + i_l) * 8);
        tile[i_l][b_l] = cvt8(src[0], src[1]);
    }
    __syncthreads();
    const int b_l = t & 63, i_s = t >> 6;         // store: 4 i x 64 b per pass
#pragma unroll
    for (int p = 0; p < 8; ++p) {
        const int i_l2 = p * 4 + i_s;
        *(short8*)(Xb + (((size_t)(it * TI + i_l2)) * BATCH + bt * TB + b_l) * 8)
            = tile[i_l2][b_l];
    }
}

// MFMA orientation (verified R3-R23): A = W (M=16 d of one j), B = X (N=16 b), K = e.
// C layout: col = lane&15 = b, row = (lane>>4)*4 + reg = d.
// MODE 0: c = 0.1 (K=32 GEMM: 4 i x 8 e).
// MODE 1: 4-i packed loads; per-i u via B-mask (kg==t); logit reduce via
//         chained 16x16x16 f16 MFMA (A=ones sums all k, C replicates L[b]).
template<int MODE>
__global__ __launch_bounds__(RTH, 2) void route_kernel(
    const short* __restrict__ Xb, const short* __restrict__ Wb,
    const short* __restrict__ zb, const float* __restrict__ V,
    float* __restrict__ S_part)
{
    __shared__ float s_lds[BT][JD + 1];
    const int tid   = threadIdx.x;
    const int lane  = tid & 63, wave = tid >> 6;
    const int icb   = blockIdx.x % NIC;
    const int btile = blockIdx.x / NIC;
    const int bcol  = lane & 15, kg = lane >> 4;
    const int b     = btile * BT + bcol;

    for (int t = tid; t < BT * (JD + 1); t += RTH) (&s_lds[0][0])[t] = 0.f;
    __syncthreads();

    if (MODE == 0) {
        f32x4 acc[J];
#pragma unroll
        for (int j = 0; j < J; ++j) acc[j] = (f32x4)(0.f);
        for (int ks = wave; ks < ICB / 4; ks += 4) {
            const int ia = icb * ICB + ks * 4 + kg;     // lane's i (k-group)
            const short8 bfr = *(const short8*)(Xb + ((size_t)ia * BATCH + b) * 8);
            short8 afr[J];
#pragma unroll
            for (int j = 0; j < J; ++j)
                afr[j] = *(const short8*)(Wb + (size_t)ia * 1280 + j * 128 + bcol * 8);
#pragma unroll
            for (int j = 0; j < J; ++j)
                acc[j] = __builtin_amdgcn_mfma_f32_16x16x32_bf16(afr[j], bfr, acc[j], 0, 0, 0);
        }
#pragma unroll
        for (int j = 0; j < J; ++j)
#pragma unroll
            for (int r = 0; r < 4; ++r)
                atomicAdd(&s_lds[bcol][j * 16 + kg * 4 + r], 0.1f * acc[j][r]);
    } else {
        float4 Vr[J];
#pragma unroll
        for (int j = 0; j < J; ++j)
            Vr[j] = *(const float4*)(V + (size_t)b * JD + j * 16 + kg * 4);

        float s_acc[J][4];
#pragma unroll
        for (int j = 0; j < J; ++j)
#pragma unroll
            for (int r = 0; r < 4; ++r) s_acc[j][r] = 0.f;

        fp16x4 ones;
        ones[0] = (__fp16)1.0f; ones[1] = (__fp16)1.0f;
        ones[2] = (__fp16)1.0f; ones[3] = (__fp16)1.0f;

        const int i0w = icb * ICB + wave * IPW;
        const short8 zero8 = (short8)(short)0;

        // 5 groups: 4 full (4 i each) + 1 tail (2 i). Loads are 4-i packed:
        // lane kg carries i = ibase + kg for ALL 64 lanes (no zero-lane waste).
#pragma unroll
        for (int g = 0; g < 5; ++g) {
            const int nt = (g < 4) ? 4 : 2;           // sub-steps this group
            int ia = i0w + g * 4 + kg;
            if (ia > IN_CAPS - 1) ia = IN_CAPS - 1;   // tail clamp (masked away)

            short8 afr[J];
#pragma unroll
            for (int j = 0; j < J; ++j)
                afr[j] = *(const short8*)(Wb + (size_t)ia * 1280 + j * 128 + bcol * 8);
            const short8 bfull = *(const short8*)(Xb + ((size_t)ia * BATCH + b) * 8);

            for (int t = 0; t < nt; ++t) {
                // B-mask: zero outside k-block t -> MFMA yields u for i_t only
                const short8 bt = (kg == t) ? bfull : zero8;
                f32x4 u[J];
#pragma unroll
                for (int j = 0; j < J; ++j)
                    u[j] = __builtin_amdgcn_mfma_f32_16x16x32_bf16(afr[j], bt, (f32x4)(0.f), 0, 0, 0);

                // logit reduce via chained MFMA: p = u*V (4 FMA), pack f16,
                // mfma(ones, p): sums ALL k (= all d across kg) per column b
                // and replicates the result to every lane of that column.
                float L[J];
#pragma unroll
                for (int j = 0; j < J; ++j) {
                    const float p0 = u[j][0] * Vr[j].x;
                    const float p1 = u[j][1] * Vr[j].y;
                    const float p2 = u[j][2] * Vr[j].z;
                    const float p3 = u[j][3] * Vr[j].w;
                    const fp16x2 a01 = __builtin_amdgcn_cvt_pkrtz(p0, p1);
                    const fp16x2 a23 = __builtin_amdgcn_cvt_pkrtz(p2, p3);
                    fp16x4 pb;
                    pb[0] = a01[0]; pb[1] = a01[1];
                    pb[2] = a23[0]; pb[3] = a23[1];
                    const f32x4 Lr = __builtin_amdgcn_mfma_f32_16x16x16f16(
                        ones, pb, (f32x4)(0.f), 0, 0, 0);
                    L[j] = Lr[0];
                }
                // softmax over j (logits bounded, |L| < 1: no max-sub needed)
                float c[J], Z = 0.f;
#pragma unroll
                for (int j = 0; j < J; ++j) { c[j] = __expf(L[j]); Z += c[j]; }
                const float rz = 1.0f / Z;
#pragma unroll
                for (int j = 0; j < J; ++j) {
                    const float cj = c[j] * rz;
                    s_acc[j][0] += cj * u[j][0];
                    s_acc[j][1] += cj * u[j][1];
                    s_acc[j][2] += cj * u[j][2];
                    s_acc[j][3] += cj * u[j][3];
                }
            }
        }
#pragma unroll
        for (int j = 0; j < J; ++j)
#pragma unroll
            for (int r = 0; r < 4; ++r)
                atomicAdd(&s_lds[bcol][j * 16 + kg * 4 + r], s_acc[j][r]);
    }
    __syncthreads();

    for (int t = tid; t < BT * JD; t += RTH) {
        const int bb = t / JD, p = t % JD;
        S_part[((size_t)icb * BATCH + btile * BT + bb) * JD + p] = s_lds[bb][p];
    }
}

// mode: 0 -> V = v, 1 -> V += v, 2 -> out = v
__global__ __launch_bounds__(256) void squash_kernel(
    const float* __restrict__ S_part, float* __restrict__ V,
    float* __restrict__ out, int mode)
{
    const int t = blockIdx.x * 256 + threadIdx.x;  // BATCH*JD threads
    float s = 0.f;
#pragma unroll
    for (int ic = 0; ic < NIC; ic++)
        s += S_part[(size_t)ic * BATCH * JD + t];
    float sq = s * s;
    sq += __shfl_xor(sq, 1);
    sq += __shfl_xor(sq, 2);
    sq += __shfl_xor(sq, 4);
    sq += __shfl_xor(sq, 8);
    const float v = s * sq / ((1.f + sq) * sqrtf(sq + 1e-8f));
    if (mode == 0)      V[t] = v;
    else if (mode == 1) V[t] += v;
    else                out[t] = v;
}

extern "C" void kernel_launch(void* const* d_in, const int* in_sizes, int n_in,
                              void* d_out, int out_size, void* d_ws, size_t ws_size,
                              hipStream_t stream)
{
    const float* X = (const float*)d_in[0];   // [512][1152][8]
    const float* W = (const float*)d_in[1];   // [1152][10][16][8]
    float* out = (float*)d_out;               // [512][10][16]

    // ws: S_part[16][512][160] f32 (5.24MB) | V[512][160] f32 | Wb bf16 (2.95MB)
    //   | Xb bf16 [1152][512][8] (9.44MB) | zb (64B zeros)   total ~18.0 MB
    float* S_part = (float*)d_ws;
    float* V      = S_part + (size_t)NIC * BATCH * JD;
    short* Wb     = (short*)(V + (size_t)BATCH * JD);
    short* Xb     = Wb + (size_t)IN_CAPS * JD * 8;
    short* zb     = Xb + (size_t)IN_CAPS * BATCH * 8;

    const dim3 rg(NBT * NIC), rb(RTH);        // 512 blocks x 4 waves
    const dim3 sg(BATCH * JD / 256), sb(256); // 320 blocks

    convert_w<<<dim3(720), dim3(256), 0, stream>>>(W, Wb, zb);
    transpose_x<<<dim3((IN_CAPS / TI) * (BATCH / TB)), dim3(256), 0, stream>>>(X, Xb);

    route_kernel<0><<<rg, rb, 0, stream>>>(Xb, Wb, zb, V, S_part);
    squash_kernel<<<sg, sb, 0, stream>>>(S_part, V, out, 0);   // V = v0
    route_kernel<1><<<rg, rb, 0, stream>>>(Xb, Wb, zb, V, S_part);
    squash_kernel<<<sg, sb, 0, stream>>>(S_part, V, out, 1);   // V += v1
    route_kernel<1><<<rg, rb, 0, stream>>>(Xb, Wb, zb, V, S_part);
    squash_kernel<<<sg, sb, 0, stream>>>(S_part, V, out, 2);   // out = v2
}